// Round 1
// baseline (2398.475 us; speedup 1.0000x reference)
//
#include <hip/hip_runtime.h>
#include <math.h>

#define B_     2
#define S_     1500
#define HID_   1024
#define NH_    16
#define HD_    64
#define KCLIP_ 64
#define NREL_  129          // 2*KCLIP+1
#define M_     (B_ * S_)    // 3000

// ---------------------------------------------------------------------------
// Tiled fp32 GEMM: C(64x64 tile) = A[M x 1024] * B + bias
// B addressing: addr = z*hs + k*rs + col   (col = 0..63 within the N-tile)
//   proj:  hs = 1024*64, rs = 64   (Wq/Wk/Wv stacked per head; N-tile == head)
//   final: hs = 64,      rs = 1024 (W_fc row-major)
// storeMode 0: C laid out [B][NH][S][HD]   (per-head Q/K/V)
// storeMode 1: C laid out [M][1024]        (row-major)
// ---------------------------------------------------------------------------
__global__ __launch_bounds__(256) void gemm_kernel(
    const float* __restrict__ A, const float* __restrict__ Bm,
    const float* __restrict__ bias, float* __restrict__ C,
    int hs, int rs, int storeMode)
{
    __shared__ float As[32][68];   // [k][m], padded (68: float4-aligned, low conflict)
    __shared__ float Bs[32][64];   // [k][n]

    const int tid = threadIdx.x;
    const int ty = tid >> 4, tx = tid & 15;   // 16x16 threads, 4x4 micro-tile
    const int m0 = blockIdx.x * 64;
    const int z  = blockIdx.y;                // N-tile (== head for proj)

    float acc[4][4] = {};

    for (int k0 = 0; k0 < HID_; k0 += 32) {
        // ---- stage A tile: 64 rows x 32 cols ----
#pragma unroll
        for (int i = 0; i < 2; ++i) {
            int t = tid + i * 256;
            int r = t >> 3, cg = (t & 7) * 4;
            int m = m0 + r;
            float4 v = make_float4(0.f, 0.f, 0.f, 0.f);
            if (m < M_) v = *(const float4*)(A + (size_t)m * HID_ + k0 + cg);
            As[cg + 0][r] = v.x; As[cg + 1][r] = v.y;
            As[cg + 2][r] = v.z; As[cg + 3][r] = v.w;
        }
        // ---- stage B tile: 32 rows x 64 cols ----
#pragma unroll
        for (int i = 0; i < 2; ++i) {
            int t = tid + i * 256;
            int r = t >> 4, cg = (t & 15) * 4;
            float4 v = *(const float4*)(Bm + (size_t)z * hs + (size_t)(k0 + r) * rs + cg);
            *(float4*)(&Bs[r][cg]) = v;
        }
        __syncthreads();

#pragma unroll
        for (int kk = 0; kk < 32; ++kk) {
            float4 av = *(const float4*)(&As[kk][ty * 4]);
            float4 bv = *(const float4*)(&Bs[kk][tx * 4]);
            float a[4] = {av.x, av.y, av.z, av.w};
            float b[4] = {bv.x, bv.y, bv.z, bv.w};
#pragma unroll
            for (int i = 0; i < 4; ++i)
#pragma unroll
                for (int j = 0; j < 4; ++j)
                    acc[i][j] = fmaf(a[i], b[j], acc[i][j]);
        }
        __syncthreads();
    }

    // ---- bias + store ----
    float bb[4];
#pragma unroll
    for (int j = 0; j < 4; ++j) bb[j] = bias[z * 64 + tx * 4 + j];

#pragma unroll
    for (int i = 0; i < 4; ++i) {
        int m = m0 + ty * 4 + i;
        if (m >= M_) continue;
        int batch = m / S_;
        int s = m - batch * S_;
        size_t base;
        if (storeMode == 0)
            base = ((size_t)(batch * NH_ + z) * S_ + s) * HD_;   // [B][NH][S][HD]
        else
            base = (size_t)m * HID_ + (size_t)z * 64;            // [M][1024]
#pragma unroll
        for (int j = 0; j < 4; ++j)
            C[base + tx * 4 + j] = acc[i][j] + bb[j];
    }
}

// ---------------------------------------------------------------------------
// Fused attention with Shaw relative position bias.
// One block (512 threads) per (b*NH+n, 16 q-rows). Full score rows in LDS.
// ---------------------------------------------------------------------------
__global__ __launch_bounds__(512) void attn_kernel(
    const float* __restrict__ Q, const float* __restrict__ K,
    const float* __restrict__ V, const float* __restrict__ pe_k,
    const float* __restrict__ pe_v, float* __restrict__ hidden)
{
    __shared__ float Qs[16][68];        //  4.25 KB
    __shared__ float qpe[16][132];      //  8.25 KB  Q . pe_k[j]
    __shared__ float Sc[16][S_];        // 93.75 KB  score rows
    __shared__ float Ks[64][65];        // 16.25 KB  K/V chunk, pad-65 (conflict-free)
    __shared__ float wsum[16][132];     //  8.25 KB  relative-bucket sums of w

    const int tid = threadIdx.x;
    const int bz = blockIdx.y;                 // b*16 + head
    const int q0 = blockIdx.x * 16;
    const int rows = min(16, S_ - q0);
    const size_t kvbase = (size_t)bz * S_ * HD_;

    // ---- Phase 0: stage Q rows ----
    for (int t = tid; t < rows * 64; t += 512) {
        int r = t >> 6, d = t & 63;
        Qs[r][d] = Q[kvbase + (size_t)(q0 + r) * 64 + d];
    }
    __syncthreads();

    // ---- Phase 1: qpe[r][j] = Q[r] . pe_k[j] ----
    for (int t = tid; t < rows * NREL_; t += 512) {
        int r = t / NREL_, j = t - r * NREL_;
        const float* pk = pe_k + j * 64;
        float s = 0.f;
#pragma unroll
        for (int d = 0; d < 64; d += 4) {
            float4 qv = *(const float4*)(&Qs[r][d]);
            s = fmaf(qv.x, pk[d + 0], s);
            s = fmaf(qv.y, pk[d + 1], s);
            s = fmaf(qv.z, pk[d + 2], s);
            s = fmaf(qv.w, pk[d + 3], s);
        }
        qpe[r][j] = s;
    }
    __syncthreads();

    // ---- Phase 2: scores = (Q.K^T + rel_bias) / 8 ----
    for (int kc = 0; kc < S_; kc += 64) {
        const int cl = min(64, S_ - kc);
        for (int t = tid; t < cl * 16; t += 512) {     // stage K chunk
            int kl = t >> 4, dg = (t & 15) * 4;
            float4 v = *(const float4*)(K + kvbase + (size_t)(kc + kl) * 64 + dg);
            Ks[kl][dg + 0] = v.x; Ks[kl][dg + 1] = v.y;
            Ks[kl][dg + 2] = v.z; Ks[kl][dg + 3] = v.w;
        }
        __syncthreads();
        for (int t = tid; t < rows * 64; t += 512) {
            int r = t >> 6, kl = t & 63;
            if (kl < cl) {
                float s = 0.f;
#pragma unroll 16
                for (int d = 0; d < 64; ++d)
                    s = fmaf(Qs[r][d], Ks[kl][d], s);
                int k = kc + kl;
                int rel = k - (q0 + r);
                rel = rel < -KCLIP_ ? -KCLIP_ : (rel > KCLIP_ ? KCLIP_ : rel);
                Sc[r][k] = (s + qpe[r][rel + KCLIP_]) * 0.125f;
            }
        }
        __syncthreads();
    }

    // ---- Phase 3: per-row softmax + relative buckets ----
    {
        const int lane = tid & 63, wv = tid >> 6;   // 8 waves
        for (int r = wv; r < rows; r += 8) {
            float m = -1e30f;
            for (int k = lane; k < S_; k += 64) m = fmaxf(m, Sc[r][k]);
#pragma unroll
            for (int off = 32; off; off >>= 1) m = fmaxf(m, __shfl_xor(m, off));
            float l = 0.f;
            for (int k = lane; k < S_; k += 64) {
                float e = __expf(Sc[r][k] - m);
                Sc[r][k] = e;
                l += e;
            }
#pragma unroll
            for (int off = 32; off; off >>= 1) l += __shfl_xor(l, off);
            float inv = 1.0f / l;
            for (int k = lane; k < S_; k += 64) Sc[r][k] *= inv;

            // relative buckets: j=0 -> k<=q-64 ; j=128 -> k>=q+64 ; middle single
            int q = q0 + r;
            float s0 = 0.f, s1 = 0.f;
            for (int k = lane; k <= q - 64; k += 64) s0 += Sc[r][k];
            for (int k = q + 64 + lane; k < S_; k += 64) s1 += Sc[r][k];
#pragma unroll
            for (int off = 32; off; off >>= 1) {
                s0 += __shfl_xor(s0, off);
                s1 += __shfl_xor(s1, off);
            }
            if (lane == 0) { wsum[r][0] = s0; wsum[r][128] = s1; }
            for (int j = 1 + lane; j < 128; j += 64) {
                int k = q + j - 64;
                wsum[r][j] = (k >= 0 && k < S_) ? Sc[r][k] : 0.f;
            }
        }
    }
    __syncthreads();

    // ---- Phase 4: out = w.V + wsum.pe_v ; store to hidden [B][S][NH*HD] ----
    {
        const int r0 = tid >> 6;        // 0..7
        const int r1 = r0 + 8;          // 8..15
        const int d0 = tid & 63;
        float acc0 = 0.f, acc1 = 0.f;

        for (int kc = 0; kc < S_; kc += 64) {
            const int cl = min(64, S_ - kc);
            for (int t = tid; t < cl * 16; t += 512) {   // stage V chunk
                int kl = t >> 4, dg = (t & 15) * 4;
                float4 v = *(const float4*)(V + kvbase + (size_t)(kc + kl) * 64 + dg);
                Ks[kl][dg + 0] = v.x; Ks[kl][dg + 1] = v.y;
                Ks[kl][dg + 2] = v.z; Ks[kl][dg + 3] = v.w;
            }
            __syncthreads();
#pragma unroll 8
            for (int kk = 0; kk < 64; ++kk) {
                if (kk < cl) {
                    float vv = Ks[kk][d0];
                    acc0 = fmaf(Sc[r0][kc + kk], vv, acc0);
                    acc1 = fmaf(Sc[r1][kc + kk], vv, acc1);
                }
            }
            __syncthreads();
        }

        // relative-value bias via bucket sums
        for (int j = 0; j < NREL_; ++j) {
            float pv = pe_v[j * 64 + d0];
            acc0 = fmaf(wsum[r0][j], pv, acc0);
            acc1 = fmaf(wsum[r1][j], pv, acc1);
        }

        const int b = bz >> 4, n = bz & 15;
        if (r0 < rows)
            hidden[((size_t)b * S_ + q0 + r0) * HID_ + n * 64 + d0] = acc0;
        if (r1 < rows)
            hidden[((size_t)b * S_ + q0 + r1) * HID_ + n * 64 + d0] = acc1;
    }
}

// ---------------------------------------------------------------------------
extern "C" void kernel_launch(void* const* d_in, const int* in_sizes, int n_in,
                              void* d_out, int out_size, void* d_ws, size_t ws_size,
                              hipStream_t stream)
{
    const float* query = (const float*)d_in[0];
    const float* key   = (const float*)d_in[1];
    const float* value = (const float*)d_in[2];
    const float* Wq    = (const float*)d_in[3];
    const float* bq    = (const float*)d_in[4];
    const float* Wk    = (const float*)d_in[5];
    const float* bk    = (const float*)d_in[6];
    const float* Wv    = (const float*)d_in[7];
    const float* bv    = (const float*)d_in[8];
    const float* pe_k  = (const float*)d_in[9];
    const float* pe_v  = (const float*)d_in[10];
    const float* W_fc  = (const float*)d_in[11];
    const float* b_fc  = (const float*)d_in[12];

    float* ws  = (float*)d_ws;
    float* Qp  = ws;                 // [B][NH][S][HD] = 3,072,000 floats
    float* Kp  = ws + 3072000;
    float* Vp  = ws + 6144000;
    float* hid = ws + 9216000;       // [B][S][HID]    = 3,072,000 floats

    dim3 gg((M_ + 63) / 64, NH_);    // 47 x 16 tiles

    gemm_kernel<<<gg, 256, 0, stream>>>(query, Wq, bq, Qp, HID_ * HD_, HD_, 0);
    gemm_kernel<<<gg, 256, 0, stream>>>(key,   Wk, bk, Kp, HID_ * HD_, HD_, 0);
    gemm_kernel<<<gg, 256, 0, stream>>>(value, Wv, bv, Vp, HID_ * HD_, HD_, 0);

    attn_kernel<<<dim3((S_ + 15) / 16, B_ * NH_), 512, 0, stream>>>(
        Qp, Kp, Vp, pe_k, pe_v, hid);

    gemm_kernel<<<gg, 256, 0, stream>>>(hid, W_fc, b_fc, (float*)d_out, HD_, HID_, 1);
}

// Round 2
// 384.662 us; speedup vs baseline: 6.2353x; 6.2353x over previous
//
#include <hip/hip_runtime.h>
#include <math.h>

#define B_     2
#define S_     1500
#define HID_   1024
#define NH_    16
#define HD_    64
#define M_     (B_*S_)   // 3000

typedef short bf16x8 __attribute__((ext_vector_type(8)));
typedef float f32x4  __attribute__((ext_vector_type(4)));

__device__ __forceinline__ float b2f(short s) {
    unsigned u = ((unsigned)(unsigned short)s) << 16;
    return __uint_as_float(u);
}
__device__ __forceinline__ short f2b(float f) {   // RNE, finite inputs
    unsigned u = __float_as_uint(f);
    unsigned r = (u + 0x7FFFu + ((u >> 16) & 1u)) >> 16;
    return (short)r;
}

// ---------------------------------------------------------------------------
// elementwise f32 -> bf16 (8 per thread)
__global__ __launch_bounds__(256) void cvt_act(const float* __restrict__ in,
                                               short* __restrict__ out, int n8) {
    int i = blockIdx.x * 256 + threadIdx.x;
    if (i >= n8) return;
    const float4* p = (const float4*)(in + (size_t)i * 8);
    float4 a = p[0], b = p[1];
    bf16x8 v;
    v[0]=f2b(a.x); v[1]=f2b(a.y); v[2]=f2b(a.z); v[3]=f2b(a.w);
    v[4]=f2b(b.x); v[5]=f2b(b.y); v[6]=f2b(b.z); v[7]=f2b(b.w);
    *(bf16x8*)(out + (size_t)i * 8) = v;
}

// ---------------------------------------------------------------------------
// weight transpose+convert: in f32 [H][R][C] -> out bf16 [H*C][R] (rows = n),
// optional residual (lo) output, scale applied before split.
__global__ __launch_bounds__(256) void tpose_w(const float* __restrict__ in,
        short* __restrict__ out_hi, short* __restrict__ out_lo,
        int R, int C, float scale) {
    __shared__ float T[64][65];
    int h = blockIdx.z, c0 = blockIdx.x * 64, r0 = blockIdx.y * 64;
    const float* src = in + ((size_t)h * R + r0) * C + c0;
    int tid = threadIdx.x;
#pragma unroll
    for (int i = 0; i < 4; ++i) {
        int slot = tid + i * 256;             // 1024 x float4
        int r = slot >> 4, cg = (slot & 15) * 4;
        float4 v = *(const float4*)(src + (size_t)r * C + cg);
        T[r][cg+0] = v.x*scale; T[r][cg+1] = v.y*scale;
        T[r][cg+2] = v.z*scale; T[r][cg+3] = v.w*scale;
    }
    __syncthreads();
#pragma unroll
    for (int i = 0; i < 16; ++i) {
        int slot = tid + i * 256;             // 4096 elems
        int c = slot >> 6, r = slot & 63;
        float v = T[r][c];
        short hi = f2b(v);
        size_t o = ((size_t)h * C + c0 + c) * (size_t)R + r0 + r;
        out_hi[o] = hi;
        if (out_lo) out_lo[o] = f2b(v - b2f(hi));
    }
}

// ---------------------------------------------------------------------------
// pe_k -> bf16 [144][64] zero-padded ; pe_v -> transposed bf16 [64][160] padded
__global__ __launch_bounds__(256) void prep_pe(const float* __restrict__ pe_k,
        const float* __restrict__ pe_v, short* __restrict__ pe_kb,
        short* __restrict__ pe_vt) {
    int tid = threadIdx.x;
    for (int s = tid; s < 144 * 64; s += 256) {
        int j = s >> 6, d = s & 63;
        pe_kb[s] = (j < 129) ? f2b(pe_k[j * 64 + d]) : (short)0;
    }
    for (int s = tid; s < 64 * 160; s += 256) {
        int d = s / 160, j = s - d * 160;
        pe_vt[s] = (j < 129) ? f2b(pe_v[j * 64 + d]) : (short)0;
    }
}

// ---------------------------------------------------------------------------
// bf16 MFMA GEMM: C[M x 1024] = A[M x K] * B^T(+segments) + bias*bscale
// B rows are output columns (pre-transposed weights [n][k]).
// Virtual K = kIters*64; seg0: Ahi*Bhi, seg1: Alo*Bhi, seg2: Ahi*Blo.
// mode 0: bf16 out at [b][h][s][d]; mode 1: f32 out row-major [m][n].
__global__ __launch_bounds__(256) void gemm_mfma(
    const short* __restrict__ Ahi, const short* __restrict__ Alo,
    const short* __restrict__ Bhi, const short* __restrict__ Blo,
    const float* __restrict__ bias, float bscale,
    short* __restrict__ out_b, float* __restrict__ out_f,
    int kIters, int mode)
{
    __shared__ short As[128 * 64];
    __shared__ short Bs[128 * 64];
    const int tid = threadIdx.x, w = tid >> 6, lane = tid & 63;
    const int l15 = lane & 15, lr4 = lane >> 4;
    const int wr = w >> 1, wc = w & 1;
    const int m0 = blockIdx.x * 128, n0 = blockIdx.y * 128;

    f32x4 zf = {0.f, 0.f, 0.f, 0.f};
    f32x4 acc[4][4];
#pragma unroll
    for (int mi = 0; mi < 4; ++mi)
#pragma unroll
        for (int ni = 0; ni < 4; ++ni) acc[mi][ni] = zf;

    for (int it = 0; it < kIters; ++it) {
        int kt = it * 64;
        int seg = kt >> 10, kk0 = kt & 1023;
        const short* Aseg = (seg == 1) ? Alo : Ahi;
        const short* Bseg = (seg == 2) ? Blo : Bhi;
        __syncthreads();
#pragma unroll
        for (int i = 0; i < 4; ++i) {
            int slot = tid + i * 256;         // 1024 x 16B
            int r = slot >> 3, cb = slot & 7;
            int sm = m0 + r; sm = sm < M_ ? sm : M_ - 1;
            bf16x8 va = *(const bf16x8*)(Aseg + (size_t)sm * 1024 + kk0 + cb * 8);
            *(bf16x8*)(As + r * 64 + ((cb ^ (r & 7)) * 8)) = va;
            int rn = n0 + r;
            bf16x8 vb = *(const bf16x8*)(Bseg + (size_t)rn * 1024 + kk0 + cb * 8);
            *(bf16x8*)(Bs + r * 64 + ((cb ^ (r & 7)) * 8)) = vb;
        }
        __syncthreads();
#pragma unroll
        for (int kh = 0; kh < 2; ++kh) {
            bf16x8 aF[4], bF[4];
#pragma unroll
            for (int mi = 0; mi < 4; ++mi) {
                int r = wr * 64 + mi * 16 + l15;
                aF[mi] = *(const bf16x8*)(As + r * 64 + (((kh * 4 + lr4) ^ (r & 7)) * 8));
            }
#pragma unroll
            for (int ni = 0; ni < 4; ++ni) {
                int r = wc * 64 + ni * 16 + l15;
                bF[ni] = *(const bf16x8*)(Bs + r * 64 + (((kh * 4 + lr4) ^ (r & 7)) * 8));
            }
#pragma unroll
            for (int mi = 0; mi < 4; ++mi)
#pragma unroll
                for (int ni = 0; ni < 4; ++ni)
                    acc[mi][ni] = __builtin_amdgcn_mfma_f32_16x16x32_bf16(
                        aF[mi], bF[ni], acc[mi][ni], 0, 0, 0);
        }
    }

#pragma unroll
    for (int mi = 0; mi < 4; ++mi)
#pragma unroll
        for (int rr = 0; rr < 4; ++rr) {
            int m = m0 + wr * 64 + mi * 16 + lr4 * 4 + rr;
            if (m >= M_) continue;
            int b = m / S_, s = m - b * S_;
#pragma unroll
            for (int ni = 0; ni < 4; ++ni) {
                int n = n0 + wc * 64 + ni * 16 + l15;
                float v = acc[mi][ni][rr] + bias[n] * bscale;
                if (mode == 0) {
                    int h = n >> 6, d = n & 63;
                    out_b[(((size_t)(b * NH_ + h)) * S_ + s) * HD_ + d] = f2b(v);
                } else {
                    out_f[(size_t)m * 1024 + n] = v;
                }
            }
        }
}

// ---------------------------------------------------------------------------
// Fused flash attention with Shaw relative bias, bf16 MFMA.
// Block = 256 thr (4 waves), 64 q-rows, one (b,head). Wave owns 16 q-rows.
__global__ __launch_bounds__(256) void attn_mfma(
    const short* __restrict__ Qb, const short* __restrict__ Kb,
    const short* __restrict__ Vb, const short* __restrict__ pe_kb,
    const short* __restrict__ pe_vt,
    short* __restrict__ hid_hi, short* __restrict__ hid_lo)
{
    __shared__ short Kc[64 * 64];      // [k][d] swizzled
    __shared__ short Vt[64 * 64];      // [d][k] swizzled
    __shared__ short qpe[64 * 144];    // [q][j] plain
    __shared__ short wsm[64 * 160];    // [q][j]: raw logits -> e-values
    __shared__ short PwA[4][16 * 64];  // per-wave P / out-hi, swizzled
    __shared__ short PwB[4][16 * 64];  // per-wave out-lo, swizzled

    const int tid = threadIdx.x;
    const int w = tid >> 6, lane = tid & 63;
    const int l15 = lane & 15, lr4 = lane >> 4;
    const int bh = blockIdx.y;
    const int q0 = blockIdx.x * 64;
    const size_t kv = (size_t)bh * S_ * HD_;

    // init wsm to -1e30 (unwritten middle slots must exp to 0)
    {
        short ini = f2b(-1e30f);
        bf16x8 iv;
#pragma unroll
        for (int i = 0; i < 8; ++i) iv[i] = ini;
        for (int s = tid; s < 64 * 160 / 8; s += 256)
            *(bf16x8*)(wsm + s * 8) = iv;
    }

    // stage Q (64x64) into Kc, swizzled
#pragma unroll
    for (int i = 0; i < 2; ++i) {
        int slot = tid + i * 256;
        int r = slot >> 3, cb = slot & 7;
        int sq = q0 + r; sq = sq < S_ ? sq : S_ - 1;
        bf16x8 v = *(const bf16x8*)(Qb + kv + (size_t)sq * 64 + cb * 8);
        *(bf16x8*)(Kc + r * 64 + ((cb ^ (r & 7)) * 8)) = v;
    }
    __syncthreads();

    bf16x8 qA[2];
    {
        int r = w * 16 + l15;
        qA[0] = *(const bf16x8*)(Kc + r * 64 + (((0 + lr4) ^ (r & 7)) * 8));
        qA[1] = *(const bf16x8*)(Kc + r * 64 + (((4 + lr4) ^ (r & 7)) * 8));
    }

    // qpe[q][j] = Q . pe_k[j]  (9 col tiles of 16, K=64) via MFMA
    f32x4 zf = {0.f, 0.f, 0.f, 0.f};
#pragma unroll
    for (int jt = 0; jt < 9; ++jt) {
        f32x4 a = zf;
#pragma unroll
        for (int kh = 0; kh < 2; ++kh) {
            bf16x8 bfr = *(const bf16x8*)(pe_kb + (jt * 16 + l15) * 64 + kh * 32 + lr4 * 8);
            a = __builtin_amdgcn_mfma_f32_16x16x32_bf16(qA[kh], bfr, a, 0, 0, 0);
        }
#pragma unroll
        for (int rr = 0; rr < 4; ++rr)
            qpe[(w * 16 + lr4 * 4 + rr) * 144 + jt * 16 + l15] = f2b(a[rr]);
    }

    f32x4 o[4];
#pragma unroll
    for (int t = 0; t < 4; ++t) o[t] = zf;
    float m_[4], s0_[4], s1_[4];
#pragma unroll
    for (int rr = 0; rr < 4; ++rr) { m_[rr] = -1e30f; s0_[rr] = 0.f; s1_[rr] = 0.f; }

    const int NCH = (S_ + 63) / 64;   // 24
    for (int c = 0; c < NCH; ++c) {
        const int kc = c * 64;
        __syncthreads();
        // stage K chunk (row-major swizzled)
#pragma unroll
        for (int i = 0; i < 2; ++i) {
            int slot = tid + i * 256;
            int r = slot >> 3, cb = slot & 7;
            int sk = kc + r; sk = sk < S_ ? sk : S_ - 1;
            bf16x8 v = *(const bf16x8*)(Kb + kv + (size_t)sk * 64 + cb * 8);
            *(bf16x8*)(Kc + r * 64 + ((cb ^ (r & 7)) * 8)) = v;
        }
        // stage V chunk transposed [d][k] swizzled
        {
            int k = tid >> 2, db = (tid & 3) * 16;
            int sk = kc + k; sk = sk < S_ ? sk : S_ - 1;
            const short* vp = Vb + kv + (size_t)sk * 64 + db;
            bf16x8 v0 = *(const bf16x8*)(vp);
            bf16x8 v1 = *(const bf16x8*)(vp + 8);
#pragma unroll
            for (int j = 0; j < 8; ++j) {
                int d = db + j;
                Vt[d * 64 + (((k >> 3) ^ (d & 7)) * 8) + (k & 7)] = v0[j];
            }
#pragma unroll
            for (int j = 0; j < 8; ++j) {
                int d = db + 8 + j;
                Vt[d * 64 + (((k >> 3) ^ (d & 7)) * 8) + (k & 7)] = v1[j];
            }
        }
        __syncthreads();

        // QK^T : 4 col tiles
        f32x4 sa[4];
#pragma unroll
        for (int t = 0; t < 4; ++t) {
            sa[t] = zf;
#pragma unroll
            for (int kh = 0; kh < 2; ++kh) {
                int r = t * 16 + l15;
                bf16x8 kB = *(const bf16x8*)(Kc + r * 64 + (((kh * 4 + lr4) ^ (r & 7)) * 8));
                sa[t] = __builtin_amdgcn_mfma_f32_16x16x32_bf16(qA[kh], kB, sa[t], 0, 0, 0);
            }
        }

        // logits: + relative-key bias, mask tail
        float lg[4][4];
#pragma unroll
        for (int t = 0; t < 4; ++t)
#pragma unroll
            for (int rr = 0; rr < 4; ++rr) {
                int k = kc + t * 16 + l15;
                int qrow = lr4 * 4 + rr;
                int q = q0 + w * 16 + qrow;
                int rel = k - q;
                int jc = rel < -64 ? 0 : (rel > 64 ? 128 : rel + 64);
                float v = sa[t][rr] + b2f(qpe[(w * 16 + qrow) * 144 + jc]);
                if (k >= S_) v = -1e30f;
                lg[t][rr] = v;
                if (rel > -64 && rel < 64)
                    wsm[(w * 16 + qrow) * 160 + rel + 64] = f2b(v);
            }

        // row maxes (reduce over l15 group)
        float rmax[4];
#pragma unroll
        for (int rr = 0; rr < 4; ++rr) {
            float x = fmaxf(fmaxf(lg[0][rr], lg[1][rr]), fmaxf(lg[2][rr], lg[3][rr]));
#pragma unroll
            for (int off = 1; off < 16; off <<= 1) x = fmaxf(x, __shfl_xor(x, off));
            rmax[rr] = x;
        }
        float du = fmaxf(fmaxf(rmax[0] - m_[0], rmax[1] - m_[1]),
                         fmaxf(rmax[2] - m_[2], rmax[3] - m_[3]));
        if (__any(du > 0.f)) {
#pragma unroll
            for (int rr = 0; rr < 4; ++rr) {
                float mn = fmaxf(m_[rr], rmax[rr]);
                float fac = __expf(m_[rr] - mn);
                m_[rr] = mn; s0_[rr] *= fac; s1_[rr] *= fac;
#pragma unroll
                for (int t = 0; t < 4; ++t) o[t][rr] *= fac;
            }
        }

        // p = exp, bucket sums, P write (bf16, swizzled per-wave buffer)
        float ps0[4] = {0.f,0.f,0.f,0.f}, ps1[4] = {0.f,0.f,0.f,0.f};
#pragma unroll
        for (int t = 0; t < 4; ++t)
#pragma unroll
            for (int rr = 0; rr < 4; ++rr) {
                float p = __expf(lg[t][rr] - m_[rr]);
                int k = kc + t * 16 + l15;
                int qrow = lr4 * 4 + rr;
                int q = q0 + w * 16 + qrow;
                int rel = k - q;
                if (rel <= -64) ps0[rr] += p;
                else if (rel >= 64) ps1[rr] += p;
                int cb = t * 2 + (l15 >> 3);
                PwA[w][qrow * 64 + ((cb ^ (qrow & 7)) * 8) + (l15 & 7)] = f2b(p);
            }
#pragma unroll
        for (int rr = 0; rr < 4; ++rr) {
#pragma unroll
            for (int off = 1; off < 16; off <<= 1) {
                ps0[rr] += __shfl_xor(ps0[rr], off);
                ps1[rr] += __shfl_xor(ps1[rr], off);
            }
            s0_[rr] += ps0[rr]; s1_[rr] += ps1[rr];
        }

        // PV: o += P * V
        bf16x8 pA[2];
        pA[0] = *(const bf16x8*)(PwA[w] + l15 * 64 + (((0 + lr4) ^ (l15 & 7)) * 8));
        pA[1] = *(const bf16x8*)(PwA[w] + l15 * 64 + (((4 + lr4) ^ (l15 & 7)) * 8));
#pragma unroll
        for (int t = 0; t < 4; ++t)
#pragma unroll
            for (int kh = 0; kh < 2; ++kh) {
                int r = t * 16 + l15;
                bf16x8 vB = *(const bf16x8*)(Vt + r * 64 + (((kh * 4 + lr4) ^ (r & 7)) * 8));
                o[t] = __builtin_amdgcn_mfma_f32_16x16x32_bf16(pA[kh], vB, o[t], 0, 0, 0);
            }
    }

    // ---- epilogue (all wave-local) ----
    // middle raw logits -> e-values in place; midsum per row
    float midsum[4];
#pragma unroll
    for (int rr = 0; rr < 4; ++rr) {
        int qrow = lr4 * 4 + rr;
        short* row = wsm + (w * 16 + qrow) * 160;
        bf16x8 mv = *(const bf16x8*)(row + l15 * 8);
        bf16x8 ev;
        float msv = 0.f;
#pragma unroll
        for (int jj = 0; jj < 8; ++jj) {
            float e = __expf(b2f(mv[jj]) - m_[rr]);
            ev[jj] = f2b(e);
            msv += e;
        }
        *(bf16x8*)(row + l15 * 8) = ev;
#pragma unroll
        for (int off = 1; off < 16; off <<= 1) msv += __shfl_xor(msv, off);
        midsum[rr] = msv;
    }
    float inv[4];
#pragma unroll
    for (int rr = 0; rr < 4; ++rr) {
        float l = s0_[rr] + s1_[rr] + midsum[rr];
        inv[rr] = 1.f / l;
        int qrow = lr4 * 4 + rr;
        short* row = wsm + (w * 16 + qrow) * 160;
        if (l15 == 0) {
            row[0]   = f2b(s0_[rr]);
            row[128] = f2b(s1_[rr]);
            row[144] = 0;
        } else {
            row[128 + l15] = 0;
            row[144 + l15] = 0;
        }
    }

    // relative-value bias: o += wsm(row) . pe_v^T   (K = 160)
#pragma unroll
    for (int t = 0; t < 4; ++t)
#pragma unroll
        for (int jh = 0; jh < 5; ++jh) {
            bf16x8 aW = *(const bf16x8*)(wsm + (w * 16 + l15) * 160 + jh * 32 + lr4 * 8);
            bf16x8 bW = *(const bf16x8*)(pe_vt + (t * 16 + l15) * 160 + jh * 32 + lr4 * 8);
            o[t] = __builtin_amdgcn_mfma_f32_16x16x32_bf16(aW, bW, o[t], 0, 0, 0);
        }

    // normalize
#pragma unroll
    for (int t = 0; t < 4; ++t)
#pragma unroll
        for (int rr = 0; rr < 4; ++rr) o[t][rr] *= inv[rr];

    // store hi + lo via swizzled LDS round-trip (coalesced bf16x8 global)
#pragma unroll
    for (int t = 0; t < 4; ++t)
#pragma unroll
        for (int rr = 0; rr < 4; ++rr) {
            int qrow = lr4 * 4 + rr;
            int cb = t * 2 + (l15 >> 3);
            float v = o[t][rr];
            short hi = f2b(v);
            int idx = qrow * 64 + ((cb ^ (qrow & 7)) * 8) + (l15 & 7);
            PwA[w][idx] = hi;
            PwB[w][idx] = f2b(v - b2f(hi));
        }
    {
        int b = bh >> 4, h = bh & 15;
        int rrow = lane >> 2;
        int q = q0 + w * 16 + rrow;
#pragma unroll
        for (int i = 0; i < 2; ++i) {
            int cb = (lane & 3) * 2 + i;
            bf16x8 hv = *(const bf16x8*)(PwA[w] + rrow * 64 + ((cb ^ (rrow & 7)) * 8));
            bf16x8 lv = *(const bf16x8*)(PwB[w] + rrow * 64 + ((cb ^ (rrow & 7)) * 8));
            if (q < S_) {
                size_t oo = ((size_t)(b * S_ + q)) * 1024 + h * 64 + cb * 8;
                *(bf16x8*)(hid_hi + oo) = hv;
                *(bf16x8*)(hid_lo + oo) = lv;
            }
        }
    }
}

// ---------------------------------------------------------------------------
extern "C" void kernel_launch(void* const* d_in, const int* in_sizes, int n_in,
                              void* d_out, int out_size, void* d_ws, size_t ws_size,
                              hipStream_t stream)
{
    const float* query = (const float*)d_in[0];
    const float* key   = (const float*)d_in[1];
    const float* value = (const float*)d_in[2];
    const float* Wq    = (const float*)d_in[3];
    const float* bq    = (const float*)d_in[4];
    const float* Wk    = (const float*)d_in[5];
    const float* bk    = (const float*)d_in[6];
    const float* Wv    = (const float*)d_in[7];
    const float* bv    = (const float*)d_in[8];
    const float* pe_k  = (const float*)d_in[9];
    const float* pe_v  = (const float*)d_in[10];
    const float* W_fc  = (const float*)d_in[11];
    const float* b_fc  = (const float*)d_in[12];

    char* W = (char*)d_ws;
    short* qb   = (short*)(W + 0);          // act bf16 -> later hid_hi
    short* kb   = (short*)(W + 6291456);    // act bf16 -> later hid_lo
    short* vb   = (short*)(W + 12582912);
    short* Wqt  = (short*)(W + 18874368);
    short* Wkt  = (short*)(W + 20971520);
    short* Wvt  = (short*)(W + 23068672);
    short* Wfh  = (short*)(W + 25165824);
    short* Wfl  = (short*)(W + 27262976);
    short* Qp   = (short*)(W + 29360128);
    short* Kp   = (short*)(W + 35651584);
    short* Vp   = (short*)(W + 41943040);
    short* pekb = (short*)(W + 48234496);
    short* pevt = (short*)(W + 48252928);
    short* hidh = qb;
    short* hidl = kb;

    // 1) convert activations to bf16
    cvt_act<<<1500, 256, 0, stream>>>(query, qb, 384000);
    cvt_act<<<1500, 256, 0, stream>>>(key,   kb, 384000);
    cvt_act<<<1500, 256, 0, stream>>>(value, vb, 384000);

    // 2) transpose+convert weights (score scale 1/8 folded into Wq)
    tpose_w<<<dim3(1, 16, 16), 256, 0, stream>>>(Wq, Wqt, (short*)nullptr, 1024, 64, 0.125f);
    tpose_w<<<dim3(1, 16, 16), 256, 0, stream>>>(Wk, Wkt, (short*)nullptr, 1024, 64, 1.0f);
    tpose_w<<<dim3(1, 16, 16), 256, 0, stream>>>(Wv, Wvt, (short*)nullptr, 1024, 64, 1.0f);
    tpose_w<<<dim3(16, 16, 1), 256, 0, stream>>>(W_fc, Wfh, Wfl, 1024, 1024, 1.0f);
    prep_pe<<<1, 256, 0, stream>>>(pe_k, pe_v, pekb, pevt);

    // 3) projections (MFMA): bias scale for Q = 1/8
    dim3 gg(24, 8);
    gemm_mfma<<<gg, 256, 0, stream>>>(qb, qb, Wqt, Wqt, bq, 0.125f, Qp, (float*)nullptr, 16, 0);
    gemm_mfma<<<gg, 256, 0, stream>>>(kb, kb, Wkt, Wkt, bk, 1.0f,   Kp, (float*)nullptr, 16, 0);
    gemm_mfma<<<gg, 256, 0, stream>>>(vb, vb, Wvt, Wvt, bv, 1.0f,   Vp, (float*)nullptr, 16, 0);

    // 4) fused attention
    attn_mfma<<<dim3(24, 32), 256, 0, stream>>>(Qp, Kp, Vp, pekb, pevt, hidh, hidl);

    // 5) output projection, split-bf16 (hi*Whi + lo*Whi + hi*Wlo)
    gemm_mfma<<<gg, 256, 0, stream>>>(hidh, hidl, Wfh, Wfl, b_fc, 1.0f,
                                      (short*)nullptr, (float*)d_out, 48, 1);
}

// Round 3
// 284.276 us; speedup vs baseline: 8.4372x; 1.3531x over previous
//
#include <hip/hip_runtime.h>
#include <math.h>

#define B_     2
#define S_     1500
#define HID_   1024
#define NH_    16
#define HD_    64
#define M_     (B_*S_)   // 3000
#define SP_    1536      // padded S for transposed-V rows

typedef short bf16x8 __attribute__((ext_vector_type(8)));
typedef short bf16x4 __attribute__((ext_vector_type(4)));
typedef float f32x4  __attribute__((ext_vector_type(4)));

__device__ __forceinline__ float b2f(short s) {
    unsigned u = ((unsigned)(unsigned short)s) << 16;
    return __uint_as_float(u);
}
__device__ __forceinline__ short f2b(float f) {   // RNE, finite inputs
    unsigned u = __float_as_uint(f);
    unsigned r = (u + 0x7FFFu + ((u >> 16) & 1u)) >> 16;
    return (short)r;
}
__device__ __forceinline__ void gload16(const short* src, short* lds) {
    __builtin_amdgcn_global_load_lds(
        (const __attribute__((address_space(1))) void*)src,
        (__attribute__((address_space(3))) void*)lds, 16, 0, 0);
}

// ---------------------------------------------------------------------------
// f32 -> bf16 for the three activations, one launch
__global__ __launch_bounds__(256) void cvt_act3(
    const float* __restrict__ q, const float* __restrict__ k,
    const float* __restrict__ v, short* __restrict__ oq,
    short* __restrict__ ok, short* __restrict__ ov)
{
    const float* src = blockIdx.y == 0 ? q : blockIdx.y == 1 ? k : v;
    short* dst       = blockIdx.y == 0 ? oq : blockIdx.y == 1 ? ok : ov;
    int i = blockIdx.x * 256 + threadIdx.x;      // < 384000
    const float4* p = (const float4*)(src + (size_t)i * 8);
    float4 a = p[0], b = p[1];
    bf16x8 o;
    o[0]=f2b(a.x); o[1]=f2b(a.y); o[2]=f2b(a.z); o[3]=f2b(a.w);
    o[4]=f2b(b.x); o[5]=f2b(b.y); o[6]=f2b(b.z); o[7]=f2b(b.w);
    *(bf16x8*)(dst + (size_t)i * 8) = o;
}

// ---------------------------------------------------------------------------
// all weight prep in one launch:
// z in [0,768): QKV heads (widx = z/256, h = (z%256)>>4, row-tile = z&15)
// z in [768,1024): W_fc tiles (hi+lo split)
// z == 1024: pe tables
__global__ __launch_bounds__(256) void prep_w(
    const float* __restrict__ Wq, const float* __restrict__ Wk,
    const float* __restrict__ Wv, const float* __restrict__ Wfc,
    const float* __restrict__ pe_k, const float* __restrict__ pe_v,
    short* __restrict__ Wqt, short* __restrict__ Wkt, short* __restrict__ Wvt,
    short* __restrict__ Wfh, short* __restrict__ Wfl,
    short* __restrict__ pe_kb, short* __restrict__ pe_vt)
{
    int z = blockIdx.x, tid = threadIdx.x;
    if (z == 1024) {
        for (int s = tid; s < 144 * 64; s += 256) {
            int j = s >> 6, d = s & 63;
            pe_kb[s] = (j < 129) ? f2b(pe_k[j * 64 + d]) : (short)0;
        }
        for (int s = tid; s < 64 * 160; s += 256) {
            int d = s / 160, j = s - d * 160;
            pe_vt[s] = (j < 129) ? f2b(pe_v[j * 64 + d]) : (short)0;
        }
        return;
    }
    __shared__ float T[64][65];
    const float* src; short* dhi; short* dlo = nullptr;
    int C, c0, r0; float scale = 1.f;
    if (z < 768) {
        int widx = z >> 8, rem = z & 255;
        int h = rem >> 4, rt = rem & 15;
        src = (widx == 0 ? Wq : widx == 1 ? Wk : Wv) + (size_t)h * 1024 * 64;
        dhi = (widx == 0 ? Wqt : widx == 1 ? Wkt : Wvt) + (size_t)h * 64 * 1024;
        scale = (widx == 0) ? 0.125f : 1.0f;
        C = 64; c0 = 0; r0 = rt * 64;
    } else {
        int idx = z - 768;
        src = Wfc; dhi = Wfh; dlo = Wfl;
        C = 1024; c0 = (idx >> 4) * 64; r0 = (idx & 15) * 64;
    }
#pragma unroll
    for (int i = 0; i < 4; ++i) {
        int slot = tid + i * 256;
        int r = slot >> 4, cg = (slot & 15) * 4;
        float4 v = *(const float4*)(src + (size_t)(r0 + r) * C + c0 + cg);
        T[r][cg+0] = v.x*scale; T[r][cg+1] = v.y*scale;
        T[r][cg+2] = v.z*scale; T[r][cg+3] = v.w*scale;
    }
    __syncthreads();
#pragma unroll
    for (int i = 0; i < 16; ++i) {
        int slot = tid + i * 256;
        int c = slot >> 6, r = slot & 63;
        float v = T[r][c];
        short hi = f2b(v);
        size_t o = (size_t)(c0 + c) * 1024 + r0 + r;
        dhi[o] = hi;
        if (dlo) dlo[o] = f2b(v - b2f(hi));
    }
}

// ---------------------------------------------------------------------------
// shared GEMM core: 128x128 tile, BK=64, global_load_lds staging with
// involutive XOR pre-swizzle on the SOURCE (linear LDS dest, swizzled reads)
__device__ __forceinline__ void gemm_core(
    const short* __restrict__ Ahi, const short* __restrict__ Alo,
    const short* __restrict__ Bhi, const short* __restrict__ Blo,
    int kIters, int m0, int n0, short* As, short* Bs, f32x4 (&acc)[4][4])
{
    const int tid = threadIdx.x, w = tid >> 6, lane = tid & 63;
    const int l15 = lane & 15, lr4 = lane >> 4;
    const int wr = w >> 1, wc = w & 1;

    for (int it = 0; it < kIters; ++it) {
        int kt = it * 64;
        int seg = kt >> 10, kk0 = kt & 1023;
        const short* Aseg = (seg == 1) ? Alo : Ahi;
        const short* Bseg = (seg == 2) ? Blo : Bhi;
        __syncthreads();
#pragma unroll
        for (int c = 0; c < 4; ++c) {
            int slot = (w * 4 + c) * 64 + lane;
            int r = slot >> 3, cb = slot & 7;
            int sm = m0 + r; sm = sm < M_ ? sm : M_ - 1;
            gload16(Aseg + (size_t)sm * 1024 + kk0 + ((cb ^ (r & 7)) * 8),
                    As + (size_t)(w * 4 + c) * 512);
            gload16(Bseg + (size_t)(n0 + r) * 1024 + kk0 + ((cb ^ (r & 7)) * 8),
                    Bs + (size_t)(w * 4 + c) * 512);
        }
        __syncthreads();
#pragma unroll
        for (int kh = 0; kh < 2; ++kh) {
            bf16x8 aF[4], bF[4];
#pragma unroll
            for (int mi = 0; mi < 4; ++mi) {
                int r = wr * 64 + mi * 16 + l15;
                aF[mi] = *(const bf16x8*)(As + r * 64 + (((kh*4+lr4) ^ (r & 7)) * 8));
            }
#pragma unroll
            for (int ni = 0; ni < 4; ++ni) {
                int r = wc * 64 + ni * 16 + l15;
                bF[ni] = *(const bf16x8*)(Bs + r * 64 + (((kh*4+lr4) ^ (r & 7)) * 8));
            }
#pragma unroll
            for (int mi = 0; mi < 4; ++mi)
#pragma unroll
                for (int ni = 0; ni < 4; ++ni)
                    acc[mi][ni] = __builtin_amdgcn_mfma_f32_16x16x32_bf16(
                        aF[mi], bF[ni], acc[mi][ni], 0, 0, 0);
        }
    }
}

// QKV projections, one launch (grid.z selects)
__global__ __launch_bounds__(256) void gemm_qkv(
    const short* __restrict__ qb, const short* __restrict__ kb,
    const short* __restrict__ vb, const short* __restrict__ Wqt,
    const short* __restrict__ Wkt, const short* __restrict__ Wvt,
    const float* __restrict__ bq, const float* __restrict__ bk,
    const float* __restrict__ bv,
    short* __restrict__ Qp, short* __restrict__ Kp, short* __restrict__ Vp)
{
    __shared__ short As[128 * 64];
    __shared__ short Bs[128 * 64];
    const int z = blockIdx.z;
    const short* A  = z == 0 ? qb : z == 1 ? kb : vb;
    const short* Bw = z == 0 ? Wqt : z == 1 ? Wkt : Wvt;
    const float* bias = z == 0 ? bq : z == 1 ? bk : bv;
    const float bscale = z == 0 ? 0.125f : 1.0f;
    short* out = z == 0 ? Qp : z == 1 ? Kp : Vp;
    const int m0 = blockIdx.x * 128, n0 = blockIdx.y * 128;

    f32x4 zf = {0.f,0.f,0.f,0.f};
    f32x4 acc[4][4];
#pragma unroll
    for (int i = 0; i < 4; ++i)
#pragma unroll
        for (int j = 0; j < 4; ++j) acc[i][j] = zf;

    gemm_core(A, A, Bw, Bw, 16, m0, n0, As, Bs, acc);

    const int tid = threadIdx.x, w = tid >> 6, lane = tid & 63;
    const int l15 = lane & 15, lr4 = lane >> 4;
    const int wr = w >> 1, wc = w & 1;
#pragma unroll
    for (int mi = 0; mi < 4; ++mi)
#pragma unroll
        for (int rr = 0; rr < 4; ++rr) {
            int m = m0 + wr * 64 + mi * 16 + lr4 * 4 + rr;
            if (m >= M_) continue;
            int b = m / S_, s = m - b * S_;
#pragma unroll
            for (int ni = 0; ni < 4; ++ni) {
                int n = n0 + wc * 64 + ni * 16 + l15;
                float v = acc[mi][ni][rr] + bias[n] * bscale;
                int h = n >> 6, d = n & 63;
                out[(((size_t)(b * NH_ + h)) * S_ + s) * HD_ + d] = f2b(v);
            }
        }
}

// final projection, 3-segment split-bf16, f32 out
__global__ __launch_bounds__(256) void gemm_fc(
    const short* __restrict__ Ahi, const short* __restrict__ Alo,
    const short* __restrict__ Bhi, const short* __restrict__ Blo,
    const float* __restrict__ bias, float* __restrict__ out)
{
    __shared__ short As[128 * 64];
    __shared__ short Bs[128 * 64];
    const int m0 = blockIdx.x * 128, n0 = blockIdx.y * 128;
    f32x4 zf = {0.f,0.f,0.f,0.f};
    f32x4 acc[4][4];
#pragma unroll
    for (int i = 0; i < 4; ++i)
#pragma unroll
        for (int j = 0; j < 4; ++j) acc[i][j] = zf;

    gemm_core(Ahi, Alo, Bhi, Blo, 48, m0, n0, As, Bs, acc);

    const int tid = threadIdx.x, w = tid >> 6, lane = tid & 63;
    const int l15 = lane & 15, lr4 = lane >> 4;
    const int wr = w >> 1, wc = w & 1;
#pragma unroll
    for (int mi = 0; mi < 4; ++mi)
#pragma unroll
        for (int rr = 0; rr < 4; ++rr) {
            int m = m0 + wr * 64 + mi * 16 + lr4 * 4 + rr;
            if (m >= M_) continue;
#pragma unroll
            for (int ni = 0; ni < 4; ++ni) {
                int n = n0 + wc * 64 + ni * 16 + l15;
                out[(size_t)m * 1024 + n] = acc[mi][ni][rr] + bias[n];
            }
        }
}

// ---------------------------------------------------------------------------
// V panel transpose: [bh][s][d] -> [bh][d][SP_] (pad region gets dup rows)
__global__ __launch_bounds__(256) void vtrans(
    const short* __restrict__ Vp, short* __restrict__ Vtg)
{
    __shared__ short T[64][72];
    const int bh = blockIdx.y, s0 = blockIdx.x * 64, tid = threadIdx.x;
    const size_t kv = (size_t)bh * S_ * 64;
#pragma unroll
    for (int i = 0; i < 2; ++i) {
        int slot = tid + i * 256;
        int r = slot >> 3, cb = slot & 7;
        int ss = s0 + r; ss = ss < S_ ? ss : S_ - 1;
        bf16x8 v = *(const bf16x8*)(Vp + kv + (size_t)ss * 64 + cb * 8);
        *(bf16x8*)(&T[r][cb * 8]) = v;
    }
    __syncthreads();
#pragma unroll
    for (int i = 0; i < 2; ++i) {
        int slot = tid + i * 256;
        int d = slot >> 3, cg = slot & 7;
        bf16x8 v;
#pragma unroll
        for (int j = 0; j < 8; ++j) v[j] = T[cg * 8 + j][d];
        *(bf16x8*)(Vtg + ((size_t)bh * 64 + d) * SP_ + s0 + cg * 8) = v;
    }
}

// ---------------------------------------------------------------------------
// Fused flash attention, swapped-QK^T layout (lane owns one q-row).
// 256 thr / 4 waves, 64 q-rows per block, one (b,head) per blockIdx.y.
__global__ __launch_bounds__(256) void attn_mfma(
    const short* __restrict__ Qb, const short* __restrict__ Kb,
    const short* __restrict__ Vtg, const short* __restrict__ pe_kb,
    const short* __restrict__ pe_vt,
    short* __restrict__ hid_hi, short* __restrict__ hid_lo)
{
    __shared__ short Kc[64 * 64];       // K chunk (also Q at start), linear-dest swizzled
    __shared__ short Vt[64 * 64];       // V^T chunk [d][k]
    __shared__ short qpe[64 * 144];     // [row][j] Shaw key-bias
    __shared__ short wsm[64 * 160];     // [row][j] raw band logits -> e-values
    __shared__ short Pw[4][16 * 64];    // per-wave P [q][k], XOR-swizzled qwords

    const int tid = threadIdx.x, w = tid >> 6, lane = tid & 63;
    const int l15 = lane & 15, lr4 = lane >> 4;
    const int bh = blockIdx.y, q0 = blockIdx.x * 64;
    const int qw = q0 + w * 16;
    const int myq = qw + l15;           // lane's q row
    const int myrow = w * 16 + l15;     // LDS row
    const size_t kv  = (size_t)bh * S_ * HD_;
    const size_t vtb = (size_t)bh * 64 * SP_;
    const int swz = (l15 & 7) << 1;

    // init wsm to -1e30
    {
        short ini = f2b(-1e30f);
        bf16x8 iv;
#pragma unroll
        for (int i = 0; i < 8; ++i) iv[i] = ini;
        for (int s = tid; s < 64 * 160 / 8; s += 256)
            *(bf16x8*)(wsm + (size_t)s * 8) = iv;
    }
    // stage Q (pre-swizzled source, linear dest)
#pragma unroll
    for (int c = 0; c < 2; ++c) {
        int slot = (w * 2 + c) * 64 + lane;
        int r = slot >> 3, cb = slot & 7;
        int sq = q0 + r; sq = sq < S_ ? sq : S_ - 1;
        gload16(Qb + kv + (size_t)sq * 64 + ((cb ^ (r & 7)) * 8),
                Kc + (size_t)(w * 2 + c) * 512);
    }
    __syncthreads();

    bf16x8 qA[2];
    {
        int r = myrow;
        qA[0] = *(const bf16x8*)(Kc + r * 64 + ((lr4 ^ (r & 7)) * 8));
        qA[1] = *(const bf16x8*)(Kc + r * 64 + (((4 + lr4) ^ (r & 7)) * 8));
    }

    // qpe^T: D[j][q] = pe_k . Q ; lane col = q = l15 -> write own row, b64 packs
    f32x4 zf = {0.f,0.f,0.f,0.f};
#pragma unroll
    for (int jt = 0; jt < 9; ++jt) {
        f32x4 a = zf;
#pragma unroll
        for (int kh = 0; kh < 2; ++kh) {
            bf16x8 pf = *(const bf16x8*)(pe_kb + (size_t)(jt * 16 + l15) * 64 + kh * 32 + lr4 * 8);
            a = __builtin_amdgcn_mfma_f32_16x16x32_bf16(pf, qA[kh], a, 0, 0, 0);
        }
        bf16x4 pk;
#pragma unroll
        for (int rr = 0; rr < 4; ++rr) pk[rr] = f2b(a[rr]);
        *(bf16x4*)(qpe + (size_t)myrow * 144 + jt * 16 + lr4 * 4) = pk;
    }
    __syncthreads();   // Kc free for K chunks; qpe rows are wave-local

    const float qpe0   = b2f(qpe[myrow * 144 + 0]);
    const float qpe128 = b2f(qpe[myrow * 144 + 128]);

    float m = -1e30f, s0s = 0.f, s1s = 0.f;
    f32x4 o[4];
#pragma unroll
    for (int t = 0; t < 4; ++t) o[t] = zf;

    for (int c = 0; c < 24; ++c) {
        const int kc = c * 64;
        __syncthreads();
        // stage K + V^T chunks
#pragma unroll
        for (int cc = 0; cc < 2; ++cc) {
            int slot = (w * 2 + cc) * 64 + lane;
            int r = slot >> 3, cb = slot & 7;
            int sk = kc + r; sk = sk < S_ ? sk : S_ - 1;
            gload16(Kb + kv + (size_t)sk * 64 + ((cb ^ (r & 7)) * 8),
                    Kc + (size_t)(w * 2 + cc) * 512);
            gload16(Vtg + vtb + (size_t)r * SP_ + kc + ((cb ^ (r & 7)) * 8),
                    Vt + (size_t)(w * 2 + cc) * 512);
        }
        __syncthreads();

        // swapped QK^T: sa[t][rr] = S[q=myq][k=kc+t*16+lr4*4+rr]
        f32x4 sa[4];
#pragma unroll
        for (int t = 0; t < 4; ++t) {
            sa[t] = zf;
#pragma unroll
            for (int kh = 0; kh < 2; ++kh) {
                int r = t * 16 + l15;
                bf16x8 kB = *(const bf16x8*)(Kc + r * 64 + (((kh*4+lr4) ^ (r & 7)) * 8));
                sa[t] = __builtin_amdgcn_mfma_f32_16x16x32_bf16(kB, qA[kh], sa[t], 0, 0, 0);
            }
        }

        const bool all_lo = (kc + 63 - qw) <= -64;
        const bool all_hi = (kc - (qw + 15)) >= 64;
        const bool mixed  = !(all_lo || all_hi);
        const float ubias = all_lo ? qpe0 : qpe128;

        float lg[4][4];
        float rm = -1e30f;
#pragma unroll
        for (int t = 0; t < 4; ++t)
#pragma unroll
            for (int rr = 0; rr < 4; ++rr) {
                int k = kc + t * 16 + lr4 * 4 + rr;
                int rel = k - myq;
                float v;
                if (mixed) {
                    int jc = rel < -64 ? 0 : (rel > 64 ? 128 : rel + 64);
                    v = sa[t][rr] + b2f(qpe[myrow * 144 + jc]);
                } else {
                    v = sa[t][rr] + ubias;
                }
                if (k >= S_) v = -1e30f;
                lg[t][rr] = v;
                rm = fmaxf(rm, v);
                if (mixed && rel > -64 && rel < 64)
                    wsm[myrow * 160 + rel + 64] = f2b(v);
            }
        rm = fmaxf(rm, __shfl_xor(rm, 16));
        rm = fmaxf(rm, __shfl_xor(rm, 32));

        if (__any(rm > m)) {
            float nm = fmaxf(m, rm);
            float fac = __expf(m - nm);
            m = nm; s0s *= fac; s1s *= fac;
            float fo[4];
#pragma unroll
            for (int rr = 0; rr < 4; ++rr) fo[rr] = __shfl(fac, lr4 * 4 + rr);
#pragma unroll
            for (int t = 0; t < 4; ++t)
#pragma unroll
                for (int rr = 0; rr < 4; ++rr) o[t][rr] *= fo[rr];
        }

        // p = exp, bucket partials, vectorized P writes (b64, swizzled qwords)
        float ls0 = 0.f, ls1 = 0.f;
#pragma unroll
        for (int t = 0; t < 4; ++t) {
            bf16x4 pk;
#pragma unroll
            for (int rr = 0; rr < 4; ++rr) {
                float p = __expf(lg[t][rr] - m);
                pk[rr] = f2b(p);
                if (mixed) {
                    int rel = (kc + t * 16 + lr4 * 4 + rr) - myq;
                    if (rel <= -64) ls0 += p; else if (rel >= 64) ls1 += p;
                } else if (all_lo) ls0 += p; else ls1 += p;
            }
            *(bf16x4*)(Pw[w] + l15 * 64 + (((t * 4 + lr4) ^ swz) << 2)) = pk;
        }
        ls0 += __shfl_xor(ls0, 16); ls0 += __shfl_xor(ls0, 32);
        ls1 += __shfl_xor(ls1, 16); ls1 += __shfl_xor(ls1, 32);
        s0s += ls0; s1s += ls1;

        // PV
#pragma unroll
        for (int win = 0; win < 2; ++win) {
            bf16x8 pA = *(const bf16x8*)(Pw[w] + l15 * 64 + (((win * 8 + lr4 * 2) ^ swz) << 2));
#pragma unroll
            for (int td = 0; td < 4; ++td) {
                int r = td * 16 + l15;
                bf16x8 vB = *(const bf16x8*)(Vt + r * 64 + (((win*4+lr4) ^ (r & 7)) * 8));
                o[td] = __builtin_amdgcn_mfma_f32_16x16x32_bf16(pA, vB, o[td], 0, 0, 0);
            }
        }
    }

    // ---- epilogue (wave-local) ----
    short* rowp = wsm + (size_t)myrow * 160;
    float midsum = 0.f;
#pragma unroll
    for (int cc = 0; cc < 5; ++cc) {
        int off = (cc * 4 + lr4) * 8;
        bf16x8 mv = *(const bf16x8*)(rowp + off);
        bf16x8 ev;
#pragma unroll
        for (int jj = 0; jj < 8; ++jj) {
            float e = __expf(b2f(mv[jj]) - m);
            ev[jj] = f2b(e);
            midsum += e;
        }
        *(bf16x8*)(rowp + off) = ev;
    }
    midsum += __shfl_xor(midsum, 16); midsum += __shfl_xor(midsum, 32);
    const float linv = 1.f / (s0s + s1s + midsum);
    if (lr4 == 0) { rowp[0] = f2b(s0s); rowp[128] = f2b(s1s); }

    // o += wsm-row . pe_v^T  (K = 160)
#pragma unroll
    for (int jh = 0; jh < 5; ++jh) {
        bf16x8 aW = *(const bf16x8*)(wsm + (size_t)myrow * 160 + jh * 32 + lr4 * 8);
#pragma unroll
        for (int td = 0; td < 4; ++td) {
            bf16x8 bW = *(const bf16x8*)(pe_vt + (size_t)(td * 16 + l15) * 160 + jh * 32 + lr4 * 8);
            o[td] = __builtin_amdgcn_mfma_f32_16x16x32_bf16(aW, bW, o[td], 0, 0, 0);
        }
    }

    // normalize (o rows = lr4*4+rr; inv lives on lane lr4*4+rr)
    {
        float fo[4];
#pragma unroll
        for (int rr = 0; rr < 4; ++rr) fo[rr] = __shfl(linv, lr4 * 4 + rr);
#pragma unroll
        for (int td = 0; td < 4; ++td)
#pragma unroll
            for (int rr = 0; rr < 4; ++rr) o[td][rr] *= fo[rr];
    }

    // stage hi -> Pw[w], lo -> wsm rows (both wave-local), then b128 stores
#pragma unroll
    for (int td = 0; td < 4; ++td)
#pragma unroll
        for (int rr = 0; rr < 4; ++rr) {
            int qrow = lr4 * 4 + rr;
            int d = td * 16 + l15;
            int inner = (((d >> 2) ^ ((qrow & 7) << 1)) << 2) + (d & 3);
            float v = o[td][rr];
            short hi = f2b(v);
            Pw[w][qrow * 64 + inner] = hi;
            wsm[(w * 16 + qrow) * 160 + inner] = f2b(v - b2f(hi));
        }
    {
        int b = bh >> 4, h = bh & 15;
        int qrow = lane >> 2;
        int q = q0 + w * 16 + qrow;
#pragma unroll
        for (int i = 0; i < 2; ++i) {
            int cb = (lane & 3) * 2 + i;
            int qws = (cb * 2) ^ ((qrow & 7) << 1);
            bf16x8 hv = *(const bf16x8*)(Pw[w] + qrow * 64 + qws * 4);
            bf16x8 lv = *(const bf16x8*)(wsm + (w * 16 + qrow) * 160 + qws * 4);
            if (q < S_) {
                size_t oo = ((size_t)(b * S_ + q)) * 1024 + h * 64 + cb * 8;
                *(bf16x8*)(hid_hi + oo) = hv;
                *(bf16x8*)(hid_lo + oo) = lv;
            }
        }
    }
}

// ---------------------------------------------------------------------------
extern "C" void kernel_launch(void* const* d_in, const int* in_sizes, int n_in,
                              void* d_out, int out_size, void* d_ws, size_t ws_size,
                              hipStream_t stream)
{
    const float* query = (const float*)d_in[0];
    const float* key   = (const float*)d_in[1];
    const float* value = (const float*)d_in[2];
    const float* Wq    = (const float*)d_in[3];
    const float* bq    = (const float*)d_in[4];
    const float* Wk    = (const float*)d_in[5];
    const float* bk    = (const float*)d_in[6];
    const float* Wv    = (const float*)d_in[7];
    const float* bv    = (const float*)d_in[8];
    const float* pe_k  = (const float*)d_in[9];
    const float* pe_v  = (const float*)d_in[10];
    const float* W_fc  = (const float*)d_in[11];
    const float* b_fc  = (const float*)d_in[12];

    char* W = (char*)d_ws;
    short* qb   = (short*)(W + 0);          // later: hid_hi
    short* kb   = (short*)(W + 6291456);    // later: hid_lo
    short* vb   = (short*)(W + 12582912);   // later: Vtg (transposed V)
    short* Vtg  = vb;
    short* Wqt  = (short*)(W + 18874368);
    short* Wkt  = (short*)(W + 20971520);
    short* Wvt  = (short*)(W + 23068672);
    short* Wfh  = (short*)(W + 25165824);
    short* Wfl  = (short*)(W + 27262976);
    short* Qp   = (short*)(W + 29360128);
    short* Kp   = (short*)(W + 35651584);
    short* Vp   = (short*)(W + 41943040);
    short* pekb = (short*)(W + 48234496);
    short* pevt = (short*)(W + 48252928);
    short* hidh = qb;
    short* hidl = kb;

    cvt_act3<<<dim3(1500, 3), 256, 0, stream>>>(query, key, value, qb, kb, vb);
    prep_w<<<1025, 256, 0, stream>>>(Wq, Wk, Wv, W_fc, pe_k, pe_v,
                                     Wqt, Wkt, Wvt, Wfh, Wfl, pekb, pevt);
    gemm_qkv<<<dim3(24, 8, 3), 256, 0, stream>>>(qb, kb, vb, Wqt, Wkt, Wvt,
                                                 bq, bk, bv, Qp, Kp, Vp);
    vtrans<<<dim3(24, 32), 256, 0, stream>>>(Vp, Vtg);
    attn_mfma<<<dim3(24, 32), 256, 0, stream>>>(Qp, Kp, Vtg, pekb, pevt, hidh, hidl);
    gemm_fc<<<dim3(24, 8), 256, 0, stream>>>(hidh, hidl, Wfh, Wfl, b_fc, (float*)d_out);
}

// Round 4
// 284.262 us; speedup vs baseline: 8.4376x; 1.0000x over previous
//
#include <hip/hip_runtime.h>
#include <math.h>

#define B_     2
#define S_     1500
#define HID_   1024
#define NH_    16
#define HD_    64
#define M_     (B_*S_)   // 3000
#define SP_    1536      // padded S for transposed-V rows
#define LOG2E  1.4426950408889634f

typedef short bf16x8 __attribute__((ext_vector_type(8)));
typedef short bf16x4 __attribute__((ext_vector_type(4)));
typedef float f32x4  __attribute__((ext_vector_type(4)));

__device__ __forceinline__ float b2f(short s) {
    unsigned u = ((unsigned)(unsigned short)s) << 16;
    return __uint_as_float(u);
}
__device__ __forceinline__ short f2b(float f) {   // RNE, finite inputs
    unsigned u = __float_as_uint(f);
    unsigned r = (u + 0x7FFFu + ((u >> 16) & 1u)) >> 16;
    return (short)r;
}
__device__ __forceinline__ void gload16(const short* src, short* lds) {
    __builtin_amdgcn_global_load_lds(
        (const __attribute__((address_space(1))) void*)src,
        (__attribute__((address_space(3))) void*)lds, 16, 0, 0);
}
__device__ __forceinline__ void bar() {
    asm volatile("" ::: "memory");
    __builtin_amdgcn_s_barrier();
    asm volatile("" ::: "memory");
}

// ---------------------------------------------------------------------------
// f32 -> bf16 for the three activations, one launch
__global__ __launch_bounds__(256) void cvt_act3(
    const float* __restrict__ q, const float* __restrict__ k,
    const float* __restrict__ v, short* __restrict__ oq,
    short* __restrict__ ok, short* __restrict__ ov)
{
    const float* src = blockIdx.y == 0 ? q : blockIdx.y == 1 ? k : v;
    short* dst       = blockIdx.y == 0 ? oq : blockIdx.y == 1 ? ok : ov;
    int i = blockIdx.x * 256 + threadIdx.x;      // < 384000
    const float4* p = (const float4*)(src + (size_t)i * 8);
    float4 a = p[0], b = p[1];
    bf16x8 o;
    o[0]=f2b(a.x); o[1]=f2b(a.y); o[2]=f2b(a.z); o[3]=f2b(a.w);
    o[4]=f2b(b.x); o[5]=f2b(b.y); o[6]=f2b(b.z); o[7]=f2b(b.w);
    *(bf16x8*)(dst + (size_t)i * 8) = o;
}

// ---------------------------------------------------------------------------
// all weight prep in one launch (see r3); Wq/bq now also fold log2e
__global__ __launch_bounds__(256) void prep_w(
    const float* __restrict__ Wq, const float* __restrict__ Wk,
    const float* __restrict__ Wv, const float* __restrict__ Wfc,
    const float* __restrict__ pe_k, const float* __restrict__ pe_v,
    short* __restrict__ Wqt, short* __restrict__ Wkt, short* __restrict__ Wvt,
    short* __restrict__ Wfh, short* __restrict__ Wfl,
    short* __restrict__ pe_kb, short* __restrict__ pe_vt)
{
    int z = blockIdx.x, tid = threadIdx.x;
    if (z == 1024) {
        for (int s = tid; s < 144 * 64; s += 256) {
            int j = s >> 6, d = s & 63;
            pe_kb[s] = (j < 129) ? f2b(pe_k[j * 64 + d]) : (short)0;
        }
        for (int s = tid; s < 64 * 160; s += 256) {
            int d = s / 160, j = s - d * 160;
            pe_vt[s] = (j < 129) ? f2b(pe_v[j * 64 + d]) : (short)0;
        }
        return;
    }
    __shared__ float T[64][65];
    const float* src; short* dhi; short* dlo = nullptr;
    int C, c0, r0; float scale = 1.f;
    if (z < 768) {
        int widx = z >> 8, rem = z & 255;
        int h = rem >> 4, rt = rem & 15;
        src = (widx == 0 ? Wq : widx == 1 ? Wk : Wv) + (size_t)h * 1024 * 64;
        dhi = (widx == 0 ? Wqt : widx == 1 ? Wkt : Wvt) + (size_t)h * 64 * 1024;
        scale = (widx == 0) ? 0.125f * LOG2E : 1.0f;
        C = 64; c0 = 0; r0 = rt * 64;
    } else {
        int idx = z - 768;
        src = Wfc; dhi = Wfh; dlo = Wfl;
        C = 1024; c0 = (idx >> 4) * 64; r0 = (idx & 15) * 64;
    }
#pragma unroll
    for (int i = 0; i < 4; ++i) {
        int slot = tid + i * 256;
        int r = slot >> 4, cg = (slot & 15) * 4;
        float4 v = *(const float4*)(src + (size_t)(r0 + r) * C + c0 + cg);
        T[r][cg+0] = v.x*scale; T[r][cg+1] = v.y*scale;
        T[r][cg+2] = v.z*scale; T[r][cg+3] = v.w*scale;
    }
    __syncthreads();
#pragma unroll
    for (int i = 0; i < 16; ++i) {
        int slot = tid + i * 256;
        int c = slot >> 6, r = slot & 63;
        float v = T[r][c];
        short hi = f2b(v);
        size_t o = (size_t)(c0 + c) * 1024 + r0 + r;
        dhi[o] = hi;
        if (dlo) dlo[o] = f2b(v - b2f(hi));
    }
}

// ---------------------------------------------------------------------------
// shared GEMM core: 128x128 tile, BK=64, global_load_lds staging
__device__ __forceinline__ void gemm_core(
    const short* __restrict__ Ahi, const short* __restrict__ Alo,
    const short* __restrict__ Bhi, const short* __restrict__ Blo,
    int kIters, int m0, int n0, short* As, short* Bs, f32x4 (&acc)[4][4])
{
    const int tid = threadIdx.x, w = tid >> 6, lane = tid & 63;
    const int l15 = lane & 15, lr4 = lane >> 4;
    const int wr = w >> 1, wc = w & 1;

    for (int it = 0; it < kIters; ++it) {
        int kt = it * 64;
        int seg = kt >> 10, kk0 = kt & 1023;
        const short* Aseg = (seg == 1) ? Alo : Ahi;
        const short* Bseg = (seg == 2) ? Blo : Bhi;
        __syncthreads();
#pragma unroll
        for (int c = 0; c < 4; ++c) {
            int slot = (w * 4 + c) * 64 + lane;
            int r = slot >> 3, cb = slot & 7;
            int sm = m0 + r; sm = sm < M_ ? sm : M_ - 1;
            gload16(Aseg + (size_t)sm * 1024 + kk0 + ((cb ^ (r & 7)) * 8),
                    As + (size_t)(w * 4 + c) * 512);
            gload16(Bseg + (size_t)(n0 + r) * 1024 + kk0 + ((cb ^ (r & 7)) * 8),
                    Bs + (size_t)(w * 4 + c) * 512);
        }
        __syncthreads();
#pragma unroll
        for (int kh = 0; kh < 2; ++kh) {
            bf16x8 aF[4], bF[4];
#pragma unroll
            for (int mi = 0; mi < 4; ++mi) {
                int r = wr * 64 + mi * 16 + l15;
                aF[mi] = *(const bf16x8*)(As + r * 64 + (((kh*4+lr4) ^ (r & 7)) * 8));
            }
#pragma unroll
            for (int ni = 0; ni < 4; ++ni) {
                int r = wc * 64 + ni * 16 + l15;
                bF[ni] = *(const bf16x8*)(Bs + r * 64 + (((kh*4+lr4) ^ (r & 7)) * 8));
            }
#pragma unroll
            for (int mi = 0; mi < 4; ++mi)
#pragma unroll
                for (int ni = 0; ni < 4; ++ni)
                    acc[mi][ni] = __builtin_amdgcn_mfma_f32_16x16x32_bf16(
                        aF[mi], bF[ni], acc[mi][ni], 0, 0, 0);
        }
    }
}

// QKV projections, one launch (grid.z selects)
__global__ __launch_bounds__(256) void gemm_qkv(
    const short* __restrict__ qb, const short* __restrict__ kb,
    const short* __restrict__ vb, const short* __restrict__ Wqt,
    const short* __restrict__ Wkt, const short* __restrict__ Wvt,
    const float* __restrict__ bq, const float* __restrict__ bk,
    const float* __restrict__ bv,
    short* __restrict__ Qp, short* __restrict__ Kp, short* __restrict__ Vp)
{
    __shared__ short As[128 * 64];
    __shared__ short Bs[128 * 64];
    const int z = blockIdx.z;
    const short* A  = z == 0 ? qb : z == 1 ? kb : vb;
    const short* Bw = z == 0 ? Wqt : z == 1 ? Wkt : Wvt;
    const float* bias = z == 0 ? bq : z == 1 ? bk : bv;
    const float bscale = z == 0 ? 0.125f * LOG2E : 1.0f;
    short* out = z == 0 ? Qp : z == 1 ? Kp : Vp;
    const int m0 = blockIdx.x * 128, n0 = blockIdx.y * 128;

    f32x4 zf = {0.f,0.f,0.f,0.f};
    f32x4 acc[4][4];
#pragma unroll
    for (int i = 0; i < 4; ++i)
#pragma unroll
        for (int j = 0; j < 4; ++j) acc[i][j] = zf;

    gemm_core(A, A, Bw, Bw, 16, m0, n0, As, Bs, acc);

    const int tid = threadIdx.x, w = tid >> 6, lane = tid & 63;
    const int l15 = lane & 15, lr4 = lane >> 4;
    const int wr = w >> 1, wc = w & 1;
#pragma unroll
    for (int mi = 0; mi < 4; ++mi)
#pragma unroll
        for (int rr = 0; rr < 4; ++rr) {
            int m = m0 + wr * 64 + mi * 16 + lr4 * 4 + rr;
            if (m >= M_) continue;
            int b = m / S_, s = m - b * S_;
#pragma unroll
            for (int ni = 0; ni < 4; ++ni) {
                int n = n0 + wc * 64 + ni * 16 + l15;
                float v = acc[mi][ni][rr] + bias[n] * bscale;
                int h = n >> 6, d = n & 63;
                out[(((size_t)(b * NH_ + h)) * S_ + s) * HD_ + d] = f2b(v);
            }
        }
}

// final projection, 3-segment split-bf16, f32 out
__global__ __launch_bounds__(256) void gemm_fc(
    const short* __restrict__ Ahi, const short* __restrict__ Alo,
    const short* __restrict__ Bhi, const short* __restrict__ Blo,
    const float* __restrict__ bias, float* __restrict__ out)
{
    __shared__ short As[128 * 64];
    __shared__ short Bs[128 * 64];
    const int m0 = blockIdx.x * 128, n0 = blockIdx.y * 128;
    f32x4 zf = {0.f,0.f,0.f,0.f};
    f32x4 acc[4][4];
#pragma unroll
    for (int i = 0; i < 4; ++i)
#pragma unroll
        for (int j = 0; j < 4; ++j) acc[i][j] = zf;

    gemm_core(Ahi, Alo, Bhi, Blo, 48, m0, n0, As, Bs, acc);

    const int tid = threadIdx.x, w = tid >> 6, lane = tid & 63;
    const int l15 = lane & 15, lr4 = lane >> 4;
    const int wr = w >> 1, wc = w & 1;
#pragma unroll
    for (int mi = 0; mi < 4; ++mi)
#pragma unroll
        for (int rr = 0; rr < 4; ++rr) {
            int m = m0 + wr * 64 + mi * 16 + lr4 * 4 + rr;
            if (m >= M_) continue;
#pragma unroll
            for (int ni = 0; ni < 4; ++ni) {
                int n = n0 + wc * 64 + ni * 16 + l15;
                out[(size_t)m * 1024 + n] = acc[mi][ni][rr] + bias[n];
            }
        }
}

// ---------------------------------------------------------------------------
// V panel transpose: [bh][s][d] -> [bh][d][SP_]
__global__ __launch_bounds__(256) void vtrans(
    const short* __restrict__ Vp, short* __restrict__ Vtg)
{
    __shared__ short T[64][72];
    const int bh = blockIdx.y, s0 = blockIdx.x * 64, tid = threadIdx.x;
    const size_t kv = (size_t)bh * S_ * 64;
#pragma unroll
    for (int i = 0; i < 2; ++i) {
        int slot = tid + i * 256;
        int r = slot >> 3, cb = slot & 7;
        int ss = s0 + r; ss = ss < S_ ? ss : S_ - 1;
        bf16x8 v = *(const bf16x8*)(Vp + kv + (size_t)ss * 64 + cb * 8);
        *(bf16x8*)(&T[r][cb * 8]) = v;
    }
    __syncthreads();
#pragma unroll
    for (int i = 0; i < 2; ++i) {
        int slot = tid + i * 256;
        int d = slot >> 3, cg = slot & 7;
        bf16x8 v;
#pragma unroll
        for (int j = 0; j < 8; ++j) v[j] = T[cg * 8 + j][d];
        *(bf16x8*)(Vtg + ((size_t)bh * 64 + d) * SP_ + s0 + cg * 8) = v;
    }
}

// ---------------------------------------------------------------------------
// Fused flash attention, swapped-QK^T, double-buffered K/V pipeline with
// counted vmcnt + raw barriers, exp2 domain, defer-max.
__global__ __launch_bounds__(256) void attn_mfma(
    const short* __restrict__ Qb, const short* __restrict__ Kb,
    const short* __restrict__ Vtg, const short* __restrict__ pe_kb,
    const short* __restrict__ pe_vt,
    short* __restrict__ hid_hi, short* __restrict__ hid_lo)
{
    __shared__ short Kc[2][4096];       // K chunks (buf1 holds Q in prologue)
    __shared__ short Vt[2][4096];       // V^T chunks
    __shared__ short qpe[64 * 144];     // [row][j] Shaw key-bias (log2 domain)
    __shared__ short wsm[64 * 160];     // [row][j] raw band logits -> e-values
    __shared__ short Pw[4][16 * 64];    // per-wave P, XOR-swizzled qwords

    const int tid = threadIdx.x, w = tid >> 6, lane = tid & 63;
    const int l15 = lane & 15, lr4 = lane >> 4;
    // XCD swizzle: each XCD gets 4 contiguous (b,h) panels
    const int lg = (blockIdx.x & 7) * 96 + (blockIdx.x >> 3);
    const int bh = lg / 24, bx = lg - bh * 24;
    const int q0 = bx * 64;
    const int qw = q0 + w * 16;
    const int myq = qw + l15;
    const int myrow = w * 16 + l15;
    const size_t kv  = (size_t)bh * S_ * HD_;
    const size_t vtb = (size_t)bh * 64 * SP_;
    const int swz = (l15 & 7) << 1;

    // init wsm to -1e30 (wave-local rows)
    {
        short ini = f2b(-1e30f);
        bf16x8 iv;
#pragma unroll
        for (int i = 0; i < 8; ++i) iv[i] = ini;
        short* base = wsm + w * 16 * 160;
#pragma unroll
        for (int i = 0; i < 5; ++i)
            *(bf16x8*)(base + (size_t)(i * 64 + lane) * 8) = iv;
    }
    // issue Q stage -> Kc[1]
#pragma unroll
    for (int cc = 0; cc < 2; ++cc) {
        int slot = (w * 2 + cc) * 64 + lane;
        int r = slot >> 3, cb = slot & 7;
        int sq = q0 + r; sq = sq < S_ ? sq : S_ - 1;
        gload16(Qb + kv + (size_t)sq * 64 + ((cb ^ (r & 7)) * 8),
                &Kc[1][(w * 2 + cc) * 512]);
    }
    // issue chunk0 stage -> Kc[0], Vt[0]
#pragma unroll
    for (int cc = 0; cc < 2; ++cc) {
        int slot = (w * 2 + cc) * 64 + lane;
        int r = slot >> 3, cb = slot & 7;
        gload16(Kb + kv + (size_t)r * 64 + ((cb ^ (r & 7)) * 8),
                &Kc[0][(w * 2 + cc) * 512]);
        gload16(Vtg + vtb + (size_t)r * SP_ + ((cb ^ (r & 7)) * 8),
                &Vt[0][(w * 2 + cc) * 512]);
    }
    asm volatile("s_waitcnt vmcnt(4)" ::: "memory");   // Q landed
    __builtin_amdgcn_s_barrier();
    asm volatile("" ::: "memory");

    bf16x8 qA[2];
    {
        int r = myrow;
        qA[0] = *(const bf16x8*)(&Kc[1][r * 64 + ((lr4 ^ (r & 7)) * 8)]);
        qA[1] = *(const bf16x8*)(&Kc[1][r * 64 + (((4 + lr4) ^ (r & 7)) * 8)]);
    }

    // qpe^T: D[j][q] = pe_k . Q (log2 domain via Wq scale)
    f32x4 zf = {0.f,0.f,0.f,0.f};
#pragma unroll
    for (int jt = 0; jt < 9; ++jt) {
        f32x4 a = zf;
#pragma unroll
        for (int kh = 0; kh < 2; ++kh) {
            bf16x8 pf = *(const bf16x8*)(pe_kb + (size_t)(jt * 16 + l15) * 64 + kh * 32 + lr4 * 8);
            a = __builtin_amdgcn_mfma_f32_16x16x32_bf16(pf, qA[kh], a, 0, 0, 0);
        }
        bf16x4 pk;
#pragma unroll
        for (int rr = 0; rr < 4; ++rr) pk[rr] = f2b(a[rr]);
        *(bf16x4*)(qpe + (size_t)myrow * 144 + jt * 16 + lr4 * 4) = pk;
    }
    const float qpe0   = b2f(qpe[myrow * 144 + 0]);
    const float qpe128 = b2f(qpe[myrow * 144 + 128]);
    bar();   // all waves done reading Kc[1] (Q)

    float m = -1e30f, s0s = 0.f, s1s = 0.f;
    f32x4 o[4];
#pragma unroll
    for (int t = 0; t < 4; ++t) o[t] = zf;

    for (int c = 0; c < 24; ++c) {
        const int kc = c * 64;
        const int p = c & 1;
        if (c < 23) {
            const int kcn = kc + 64;
            short* KD = Kc[1 - p]; short* VD = Vt[1 - p];
#pragma unroll
            for (int cc = 0; cc < 2; ++cc) {
                int slot = (w * 2 + cc) * 64 + lane;
                int r = slot >> 3, cb = slot & 7;
                int sk = kcn + r; sk = sk < S_ ? sk : S_ - 1;
                gload16(Kb + kv + (size_t)sk * 64 + ((cb ^ (r & 7)) * 8),
                        KD + (w * 2 + cc) * 512);
                gload16(Vtg + vtb + (size_t)r * SP_ + kcn + ((cb ^ (r & 7)) * 8),
                        VD + (w * 2 + cc) * 512);
            }
            asm volatile("s_waitcnt vmcnt(4)" ::: "memory");  // chunk c landed
        } else {
            asm volatile("s_waitcnt vmcnt(0)" ::: "memory");
        }
        __builtin_amdgcn_s_barrier();
        asm volatile("" ::: "memory");

        const short* KP = Kc[p]; const short* VP = Vt[p];

        // swapped QK^T
        __builtin_amdgcn_s_setprio(1);
        f32x4 sa[4];
#pragma unroll
        for (int t = 0; t < 4; ++t) {
            sa[t] = zf;
#pragma unroll
            for (int kh = 0; kh < 2; ++kh) {
                int r = t * 16 + l15;
                bf16x8 kB = *(const bf16x8*)(KP + r * 64 + (((kh*4+lr4) ^ (r & 7)) * 8));
                sa[t] = __builtin_amdgcn_mfma_f32_16x16x32_bf16(kB, qA[kh], sa[t], 0, 0, 0);
            }
        }
        __builtin_amdgcn_s_setprio(0);

        const bool all_lo = (kc + 63 - qw) <= -64;
        const bool all_hi = (kc - (qw + 15)) >= 64;
        const bool mixed  = !(all_lo || all_hi);
        const float ubias = all_lo ? qpe0 : qpe128;

        float lg2[4][4];
        float rm = -1e30f;
#pragma unroll
        for (int t = 0; t < 4; ++t)
#pragma unroll
            for (int rr = 0; rr < 4; ++rr) {
                int k = kc + t * 16 + lr4 * 4 + rr;
                int rel = k - myq;
                float v;
                if (mixed) {
                    int jc = rel < -64 ? 0 : (rel > 64 ? 128 : rel + 64);
                    v = sa[t][rr] + b2f(qpe[myrow * 144 + jc]);
                } else {
                    v = sa[t][rr] + ubias;
                }
                if (k >= S_) v = -1e30f;
                lg2[t][rr] = v;
                rm = fmaxf(rm, v);
                if (mixed && rel > -64 && rel < 64)
                    wsm[myrow * 160 + rel + 64] = f2b(v);
            }
        rm = fmaxf(rm, __shfl_xor(rm, 16));
        rm = fmaxf(rm, __shfl_xor(rm, 32));

        // defer-max: only rescale when growth exceeds 8 (log2 domain)
        if (!__all(rm <= m + 8.f)) {
            float nm = fmaxf(m, rm);
            float fac = exp2f(m - nm);
            m = nm; s0s *= fac; s1s *= fac;
            float fo[4];
#pragma unroll
            for (int rr = 0; rr < 4; ++rr) fo[rr] = __shfl(fac, lr4 * 4 + rr);
#pragma unroll
            for (int t = 0; t < 4; ++t)
#pragma unroll
                for (int rr = 0; rr < 4; ++rr) o[t][rr] *= fo[rr];
        }

        // p = exp2, bucket partials, vectorized P writes
        float ls0 = 0.f, ls1 = 0.f;
#pragma unroll
        for (int t = 0; t < 4; ++t) {
            bf16x4 pk;
#pragma unroll
            for (int rr = 0; rr < 4; ++rr) {
                float p2 = exp2f(lg2[t][rr] - m);
                pk[rr] = f2b(p2);
                if (mixed) {
                    int rel = (kc + t * 16 + lr4 * 4 + rr) - myq;
                    if (rel <= -64) ls0 += p2; else if (rel >= 64) ls1 += p2;
                } else if (all_lo) ls0 += p2; else ls1 += p2;
            }
            *(bf16x4*)(Pw[w] + l15 * 64 + (((t * 4 + lr4) ^ swz) << 2)) = pk;
        }
        ls0 += __shfl_xor(ls0, 16); ls0 += __shfl_xor(ls0, 32);
        ls1 += __shfl_xor(ls1, 16); ls1 += __shfl_xor(ls1, 32);
        s0s += ls0; s1s += ls1;

        // PV
        __builtin_amdgcn_s_setprio(1);
#pragma unroll
        for (int win = 0; win < 2; ++win) {
            bf16x8 pA = *(const bf16x8*)(Pw[w] + l15 * 64 + (((win * 8 + lr4 * 2) ^ swz) << 2));
#pragma unroll
            for (int td = 0; td < 4; ++td) {
                int r = td * 16 + l15;
                bf16x8 vB = *(const bf16x8*)(VP + r * 64 + (((win*4+lr4) ^ (r & 7)) * 8));
                o[td] = __builtin_amdgcn_mfma_f32_16x16x32_bf16(pA, vB, o[td], 0, 0, 0);
            }
        }
        __builtin_amdgcn_s_setprio(0);

        bar();   // all waves done reading buf p; next iter may overwrite it
    }

    // ---- epilogue (lane-local wsm traffic) ----
    short* rowp = wsm + (size_t)myrow * 160;
    float midsum = 0.f;
#pragma unroll
    for (int cc = 0; cc < 5; ++cc) {
        int off = (cc * 4 + lr4) * 8;
        bf16x8 mv = *(const bf16x8*)(rowp + off);
        bf16x8 ev;
#pragma unroll
        for (int jj = 0; jj < 8; ++jj) {
            float e = exp2f(b2f(mv[jj]) - m);
            ev[jj] = f2b(e);
            midsum += e;
        }
        *(bf16x8*)(rowp + off) = ev;
    }
    midsum += __shfl_xor(midsum, 16); midsum += __shfl_xor(midsum, 32);
    const float linv = 1.f / (s0s + s1s + midsum);
    if (lr4 == 0) { rowp[0] = f2b(s0s); rowp[128] = f2b(s1s); }

    // o += wsm-row . pe_v^T  (K = 160)
#pragma unroll
    for (int jh = 0; jh < 5; ++jh) {
        bf16x8 aW = *(const bf16x8*)(wsm + (size_t)myrow * 160 + jh * 32 + lr4 * 8);
#pragma unroll
        for (int td = 0; td < 4; ++td) {
            bf16x8 bW = *(const bf16x8*)(pe_vt + (size_t)(td * 16 + l15) * 160 + jh * 32 + lr4 * 8);
            o[td] = __builtin_amdgcn_mfma_f32_16x16x32_bf16(aW, bW, o[td], 0, 0, 0);
        }
    }

    // normalize
    {
        float fo[4];
#pragma unroll
        for (int rr = 0; rr < 4; ++rr) fo[rr] = __shfl(linv, lr4 * 4 + rr);
#pragma unroll
        for (int td = 0; td < 4; ++td)
#pragma unroll
            for (int rr = 0; rr < 4; ++rr) o[td][rr] *= fo[rr];
    }

    // stage hi -> Pw[w], lo -> wsm rows, then b128 stores
#pragma unroll
    for (int td = 0; td < 4; ++td)
#pragma unroll
        for (int rr = 0; rr < 4; ++rr) {
            int qrow = lr4 * 4 + rr;
            int d = td * 16 + l15;
            int inner = (((d >> 2) ^ ((qrow & 7) << 1)) << 2) + (d & 3);
            float v = o[td][rr];
            short hi = f2b(v);
            Pw[w][qrow * 64 + inner] = hi;
            wsm[(w * 16 + qrow) * 160 + inner] = f2b(v - b2f(hi));
        }
    {
        int b = bh >> 4, h = bh & 15;
        int qrow = lane >> 2;
        int q = q0 + w * 16 + qrow;
#pragma unroll
        for (int i = 0; i < 2; ++i) {
            int cb = (lane & 3) * 2 + i;
            int qws = (cb * 2) ^ ((qrow & 7) << 1);
            bf16x8 hv = *(const bf16x8*)(Pw[w] + qrow * 64 + qws * 4);
            bf16x8 lv = *(const bf16x8*)(wsm + (w * 16 + qrow) * 160 + qws * 4);
            if (q < S_) {
                size_t oo = ((size_t)(b * S_ + q)) * 1024 + h * 64 + cb * 8;
                *(bf16x8*)(hid_hi + oo) = hv;
                *(bf16x8*)(hid_lo + oo) = lv;
            }
        }
    }
}

// ---------------------------------------------------------------------------
extern "C" void kernel_launch(void* const* d_in, const int* in_sizes, int n_in,
                              void* d_out, int out_size, void* d_ws, size_t ws_size,
                              hipStream_t stream)
{
    const float* query = (const float*)d_in[0];
    const float* key   = (const float*)d_in[1];
    const float* value = (const float*)d_in[2];
    const float* Wq    = (const float*)d_in[3];
    const float* bq    = (const float*)d_in[4];
    const float* Wk    = (const float*)d_in[5];
    const float* bk    = (const float*)d_in[6];
    const float* Wv    = (const float*)d_in[7];
    const float* bv    = (const float*)d_in[8];
    const float* pe_k  = (const float*)d_in[9];
    const float* pe_v  = (const float*)d_in[10];
    const float* W_fc  = (const float*)d_in[11];
    const float* b_fc  = (const float*)d_in[12];

    char* W = (char*)d_ws;
    short* qb   = (short*)(W + 0);          // later: hid_hi
    short* kb   = (short*)(W + 6291456);    // later: hid_lo
    short* vb   = (short*)(W + 12582912);   // later: Vtg (transposed V)
    short* Vtg  = vb;
    short* Wqt  = (short*)(W + 18874368);
    short* Wkt  = (short*)(W + 20971520);
    short* Wvt  = (short*)(W + 23068672);
    short* Wfh  = (short*)(W + 25165824);
    short* Wfl  = (short*)(W + 27262976);
    short* Qp   = (short*)(W + 29360128);
    short* Kp   = (short*)(W + 35651584);
    short* Vp   = (short*)(W + 41943040);
    short* pekb = (short*)(W + 48234496);
    short* pevt = (short*)(W + 48252928);
    short* hidh = qb;
    short* hidl = kb;

    cvt_act3<<<dim3(1500, 3), 256, 0, stream>>>(query, key, value, qb, kb, vb);
    prep_w<<<1025, 256, 0, stream>>>(Wq, Wk, Wv, W_fc, pe_k, pe_v,
                                     Wqt, Wkt, Wvt, Wfh, Wfl, pekb, pevt);
    gemm_qkv<<<dim3(24, 8, 3), 256, 0, stream>>>(qb, kb, vb, Wqt, Wkt, Wvt,
                                                 bq, bk, bv, Qp, Kp, Vp);
    vtrans<<<dim3(24, 32), 256, 0, stream>>>(Vp, Vtg);
    attn_mfma<<<768, 256, 0, stream>>>(Qp, Kp, Vtg, pekb, pevt, hidh, hidl);
    gemm_fc<<<dim3(24, 8), 256, 0, stream>>>(hidh, hidl, Wfh, Wfl, b_fc, (float*)d_out);
}